// Round 1
// baseline (210.450 us; speedup 1.0000x reference)
//
#include <hip/hip_runtime.h>

// SNN ALIF step for B=32, N=4096, D=8, NE=2048, DE=4.
// Strategy: spikes are binary/sparse (5%) -> "GEMM" = sum of active W rows.
// K1: elementwise spike/adapt update + compact active-source index lists per batch.
// K2: per (batch, 256-col tile), accumulate active W_int/W_ext rows (float4),
//     fuse membrane update epilogue.

#define B_   32
#define N_   4096
#define D_   8
#define NE_  2048
#define DE_  4
#define BN_  (B_ * N_)
#define BNE_ (B_ * NE_)

__global__ __launch_bounds__(256) void snn_spike_scatter(
    const float* __restrict__ V, const float* __restrict__ a,
    const float* __restrict__ Xd, const float* __restrict__ Xext,
    const float* __restrict__ dmap_int, const float* __restrict__ dmap_ext,
    float* __restrict__ out, int* __restrict__ cnt,
    unsigned short* __restrict__ list_int, unsigned short* __restrict__ list_ext)
{
#pragma clang fp contract(off)
    // exact op order for th/vm: a 1-ulp difference can flip a spike (absmax 1.0)
    int t = blockIdx.x * 256 + threadIdx.x;
    if (t < BN_) {
        int b = t >> 12;          // / N_
        int i = t & (N_ - 1);
        float av = a[t];
        float vv = V[t];
        float th = 1.0f + 1.8f * av;
        float vm = vv - th;
        float x = (vm >= 0.0f) ? 1.0f : 0.0f;
        out[t] = x;                       // X
        out[2 * BN_ + t] = 0.98f * av + x; // a_new
        // delay bin for internal source i (one-hot over d)
        int di = 0;
        #pragma unroll
        for (int d = 1; d < D_; ++d)
            if (dmap_int[d * N_ + i] != 0.0f) di = d;
        // Xd_new[0] = X (current), Xd_new[d>=1] = Xd[d-1]
        float xi = (di == 0) ? x : Xd[(di - 1) * BN_ + t];
        if (xi != 0.0f) {
            int pos = atomicAdd(&cnt[b], 1);
            list_int[b * N_ + pos] = (unsigned short)i;
        }
    } else if (t < BN_ + BNE_) {
        int u = t - BN_;
        int b = u >> 11;          // / NE_
        int j = u & (NE_ - 1);
        int de = 0;
        #pragma unroll
        for (int d = 1; d < DE_; ++d)
            if (dmap_ext[d * NE_ + j] != 0.0f) de = d;
        float xe = Xext[de * BNE_ + u];   // Xext used directly (no shift)
        if (xe != 0.0f) {
            int pos = atomicAdd(&cnt[B_ + b], 1);
            list_ext[b * NE_ + pos] = (unsigned short)j;
        }
    }
}

__device__ __forceinline__ float4 ld4(const float* p) { return *(const float4*)p; }
__device__ __forceinline__ void add4(float4& a, float4 w) {
    a.x += w.x; a.y += w.y; a.z += w.z; a.w += w.w;
}

// Accumulate n rows of W (row length N_ for both W_int and W_ext) at column j.
__device__ __forceinline__ void accum_rows(const float* __restrict__ W,
                                           const unsigned short* sl, int n, int j,
                                           float4& acc)
{
    int k = 0;
    for (; k + 8 <= n; k += 8) {   // 8 independent float4 loads in flight
        float4 w0 = ld4(W + (size_t)sl[k + 0] * N_ + j);
        float4 w1 = ld4(W + (size_t)sl[k + 1] * N_ + j);
        float4 w2 = ld4(W + (size_t)sl[k + 2] * N_ + j);
        float4 w3 = ld4(W + (size_t)sl[k + 3] * N_ + j);
        float4 w4 = ld4(W + (size_t)sl[k + 4] * N_ + j);
        float4 w5 = ld4(W + (size_t)sl[k + 5] * N_ + j);
        float4 w6 = ld4(W + (size_t)sl[k + 6] * N_ + j);
        float4 w7 = ld4(W + (size_t)sl[k + 7] * N_ + j);
        add4(acc, w0); add4(acc, w1); add4(acc, w2); add4(acc, w3);
        add4(acc, w4); add4(acc, w5); add4(acc, w6); add4(acc, w7);
    }
    for (; k < n; ++k) {
        float4 w = ld4(W + (size_t)sl[k] * N_ + j);
        add4(acc, w);
    }
}

__global__ __launch_bounds__(64) void snn_current(
    const float* __restrict__ W_int, const float* __restrict__ W_ext,
    const float* __restrict__ V, float* __restrict__ out,
    const int* __restrict__ cnt,
    const unsigned short* __restrict__ list_int,
    const unsigned short* __restrict__ list_ext)
{
    __shared__ unsigned short s_int[N_];
    __shared__ unsigned short s_ext[NE_];
    int b = blockIdx.y;
    int ni = cnt[b];
    int ne = cnt[B_ + b];
    for (int k = threadIdx.x; k < ni; k += 64) s_int[k] = list_int[b * N_ + k];
    for (int k = threadIdx.x; k < ne; k += 64) s_ext[k] = list_ext[b * NE_ + k];
    __syncthreads();

    int j = blockIdx.x * 256 + threadIdx.x * 4;   // 16 tiles x 256 cols
    float4 acc = make_float4(0.f, 0.f, 0.f, 0.f);

    accum_rows(W_int, s_int, ni, j, acc);   // internal: rows of [N_, N_]
    accum_rows(W_ext, s_ext, ne, j, acc);   // external: rows of [NE_, N_] (same row len)

    // fused membrane update: V_new = ALPHA*V*(1-X) + current
    int t = b * N_ + j;
    float4 v = ld4(V + t);
    float4 x = ld4(out + t);   // X written by K1
    float4 vn;
    vn.x = 0.95f * v.x * (1.0f - x.x) + acc.x;
    vn.y = 0.95f * v.y * (1.0f - x.y) + acc.y;
    vn.z = 0.95f * v.z * (1.0f - x.z) + acc.z;
    vn.w = 0.95f * v.w * (1.0f - x.w) + acc.w;
    *(float4*)(out + BN_ + t) = vn;
}

extern "C" void kernel_launch(void* const* d_in, const int* in_sizes, int n_in,
                              void* d_out, int out_size, void* d_ws, size_t ws_size,
                              hipStream_t stream)
{
    const float* V        = (const float*)d_in[0];
    const float* a        = (const float*)d_in[1];
    const float* Xd       = (const float*)d_in[2];
    const float* Xext     = (const float*)d_in[3];
    const float* W_int    = (const float*)d_in[4];
    const float* W_ext    = (const float*)d_in[5];
    const float* dmap_int = (const float*)d_in[6];
    const float* dmap_ext = (const float*)d_in[7];
    float* out = (float*)d_out;

    int* cnt = (int*)d_ws;                                        // 64 ints
    unsigned short* list_int = (unsigned short*)((char*)d_ws + 256);
    unsigned short* list_ext = (unsigned short*)((char*)d_ws + 256 + (size_t)B_ * N_ * 2);

    hipMemsetAsync(d_ws, 0, 256, stream);   // zero counters (ws is poisoned each call)

    int total = BN_ + BNE_;
    snn_spike_scatter<<<(total + 255) / 256, 256, 0, stream>>>(
        V, a, Xd, Xext, dmap_int, dmap_ext, out, cnt, list_int, list_ext);

    dim3 g2(16, 32);
    snn_current<<<g2, 64, 0, stream>>>(W_int, W_ext, V, out, cnt, list_int, list_ext);
}

// Round 2
// 149.833 us; speedup vs baseline: 1.4046x; 1.4046x over previous
//
#include <hip/hip_runtime.h>

// SNN ALIF step, B=32, N=4096, D=8, NE=2048, DE=4.
// K1: per-(batch,chunk) block computes spikes/adaptation, compacts active
//     presyn indices via LDS atomics, ONE global atomicAdd per block to
//     reserve a merged-list segment (no hot-line atomic storm).
// K2: per (batch, 256-col tile): stage merged index lists in LDS, then
//     software-pipelined (8+8 float4 loads in flight) accumulation of active
//     W rows; fused membrane-update epilogue.

#define B_   32
#define N_   4096
#define D_   8
#define NE_  2048
#define DE_  4
#define BN_  (B_ * N_)
#define BNE_ (B_ * NE_)

// ---------------- K1: spike + compact ----------------
__global__ __launch_bounds__(256) void snn_spike_compact(
    const float* __restrict__ V, const float* __restrict__ a,
    const float* __restrict__ Xd, const float* __restrict__ Xext,
    const float* __restrict__ dmap_int, const float* __restrict__ dmap_ext,
    float* __restrict__ out, int* __restrict__ cnt,
    unsigned short* __restrict__ list_int, unsigned short* __restrict__ list_ext)
{
#pragma clang fp contract(off)
    // exact op order for th: a 1-ulp difference can flip a spike (absmax 1.0)
    __shared__ unsigned short s_i[512];
    __shared__ unsigned short s_e[256];
    __shared__ int lc_i, lc_e, base_i, base_e;
    int tid = threadIdx.x;
    if (tid == 0) { lc_i = 0; lc_e = 0; }
    __syncthreads();

    int b = blockIdx.y;
    int c = blockIdx.x;          // chunk: 512 int neurons, 256 ext sources

    // internal neurons: i in [c*512, c*512+512)
    #pragma unroll
    for (int r = 0; r < 2; ++r) {
        int i = c * 512 + r * 256 + tid;
        int t = b * N_ + i;
        float av = a[t];
        float vv = V[t];
        float th = 1.0f + 1.8f * av;
        float x = (vv - th >= 0.0f) ? 1.0f : 0.0f;
        out[t] = x;                          // X
        out[2 * BN_ + t] = 0.98f * av + x;   // a_new
        int di = 0;
        #pragma unroll
        for (int d = 1; d < D_; ++d)
            if (dmap_int[d * N_ + i] != 0.0f) di = d;
        // Xd_new[0] = X, Xd_new[d>=1] = Xd[d-1]
        float xi = (di == 0) ? x : Xd[(di - 1) * BN_ + t];
        if (xi != 0.0f) {
            int p = atomicAdd(&lc_i, 1);     // LDS atomic: cheap
            s_i[p] = (unsigned short)i;
        }
    }
    // external sources: j in [c*256, c*256+256)
    {
        int j = c * 256 + tid;
        int u = b * NE_ + j;
        int de = 0;
        #pragma unroll
        for (int d = 1; d < DE_; ++d)
            if (dmap_ext[d * NE_ + j] != 0.0f) de = d;
        float xe = Xext[de * BNE_ + u];
        if (xe != 0.0f) {
            int p = atomicAdd(&lc_e, 1);
            s_e[p] = (unsigned short)j;
        }
    }
    __syncthreads();
    if (tid == 0) {
        base_i = atomicAdd(&cnt[b], lc_i);        // 1 global atomic per block
        base_e = atomicAdd(&cnt[B_ + b], lc_e);
    }
    __syncthreads();
    for (int k = tid; k < lc_i; k += 256) list_int[b * N_  + base_i + k] = s_i[k];
    for (int k = tid; k < lc_e; k += 256) list_ext[b * NE_ + base_e + k] = s_e[k];
}

// ---------------- K2: gather-accumulate W rows ----------------
__device__ __forceinline__ float4 ld4(const float* p) { return *(const float4*)p; }
__device__ __forceinline__ void add4(float4& a, const float4 w) {
    a.x += w.x; a.y += w.y; a.z += w.z; a.w += w.w;
}

// Accumulate n rows of W (row stride N_) at column j; indices in LDS (sl).
// Software-pipelined: 8 loads in flight while previous 8 accumulate.
__device__ __forceinline__ void accum_rows(const float* __restrict__ W,
                                           const unsigned short* sl, int n, int j,
                                           float4& acc)
{
    int nf = n & ~7;
    if (nf >= 8) {
        uint4 g = *(const uint4*)(sl);   // 8 indices (LDS, lgkmcnt domain)
        float4 p0 = ld4(W + (size_t)(g.x & 0xffff) * N_ + j);
        float4 p1 = ld4(W + (size_t)(g.x >> 16)    * N_ + j);
        float4 p2 = ld4(W + (size_t)(g.y & 0xffff) * N_ + j);
        float4 p3 = ld4(W + (size_t)(g.y >> 16)    * N_ + j);
        float4 p4 = ld4(W + (size_t)(g.z & 0xffff) * N_ + j);
        float4 p5 = ld4(W + (size_t)(g.z >> 16)    * N_ + j);
        float4 p6 = ld4(W + (size_t)(g.w & 0xffff) * N_ + j);
        float4 p7 = ld4(W + (size_t)(g.w >> 16)    * N_ + j);
        for (int k = 8; k < nf; k += 8) {
            uint4 g2 = *(const uint4*)(sl + k);
            float4 q0 = ld4(W + (size_t)(g2.x & 0xffff) * N_ + j);
            float4 q1 = ld4(W + (size_t)(g2.x >> 16)    * N_ + j);
            float4 q2 = ld4(W + (size_t)(g2.y & 0xffff) * N_ + j);
            float4 q3 = ld4(W + (size_t)(g2.y >> 16)    * N_ + j);
            float4 q4 = ld4(W + (size_t)(g2.z & 0xffff) * N_ + j);
            float4 q5 = ld4(W + (size_t)(g2.z >> 16)    * N_ + j);
            float4 q6 = ld4(W + (size_t)(g2.w & 0xffff) * N_ + j);
            float4 q7 = ld4(W + (size_t)(g2.w >> 16)    * N_ + j);
            add4(acc, p0); add4(acc, p1); add4(acc, p2); add4(acc, p3);
            add4(acc, p4); add4(acc, p5); add4(acc, p6); add4(acc, p7);
            p0 = q0; p1 = q1; p2 = q2; p3 = q3;
            p4 = q4; p5 = q5; p6 = q6; p7 = q7;
        }
        add4(acc, p0); add4(acc, p1); add4(acc, p2); add4(acc, p3);
        add4(acc, p4); add4(acc, p5); add4(acc, p6); add4(acc, p7);
    }
    for (int k = nf; k < n; ++k) {
        float4 w = ld4(W + (size_t)sl[k] * N_ + j);
        add4(acc, w);
    }
}

__global__ __launch_bounds__(64) void snn_current(
    const float* __restrict__ W_int, const float* __restrict__ W_ext,
    const float* __restrict__ V, float* __restrict__ out,
    const int* __restrict__ cnt,
    const unsigned short* __restrict__ list_int,
    const unsigned short* __restrict__ list_ext)
{
    __shared__ unsigned short s_int[N_];
    __shared__ unsigned short s_ext[NE_];
    int b = blockIdx.y;
    int ni = cnt[b];
    int ne = cnt[B_ + b];
    for (int k = threadIdx.x; k < ni; k += 64) s_int[k] = list_int[b * N_  + k];
    for (int k = threadIdx.x; k < ne; k += 64) s_ext[k] = list_ext[b * NE_ + k];
    __syncthreads();

    int j = blockIdx.x * 256 + threadIdx.x * 4;   // 16 tiles x 256 cols
    float4 acc = make_float4(0.f, 0.f, 0.f, 0.f);
    accum_rows(W_int, s_int, ni, j, acc);
    accum_rows(W_ext, s_ext, ne, j, acc);

    // fused: V_new = ALPHA*V*(1-X) + current
    int t = b * N_ + j;
    float4 v = ld4(V + t);
    float4 x = ld4(out + t);      // X written by K1
    float4 vn;
    vn.x = 0.95f * v.x * (1.0f - x.x) + acc.x;
    vn.y = 0.95f * v.y * (1.0f - x.y) + acc.y;
    vn.z = 0.95f * v.z * (1.0f - x.z) + acc.z;
    vn.w = 0.95f * v.w * (1.0f - x.w) + acc.w;
    *(float4*)(out + BN_ + t) = vn;
}

extern "C" void kernel_launch(void* const* d_in, const int* in_sizes, int n_in,
                              void* d_out, int out_size, void* d_ws, size_t ws_size,
                              hipStream_t stream)
{
    const float* V        = (const float*)d_in[0];
    const float* a        = (const float*)d_in[1];
    const float* Xd       = (const float*)d_in[2];
    const float* Xext     = (const float*)d_in[3];
    const float* W_int    = (const float*)d_in[4];
    const float* W_ext    = (const float*)d_in[5];
    const float* dmap_int = (const float*)d_in[6];
    const float* dmap_ext = (const float*)d_in[7];
    float* out = (float*)d_out;

    int* cnt = (int*)d_ws;                                           // 64 ints
    unsigned short* list_int = (unsigned short*)((char*)d_ws + 256);
    unsigned short* list_ext = (unsigned short*)((char*)d_ws + 256 + (size_t)BN_ * 2);

    hipMemsetAsync(d_ws, 0, 256, stream);   // zero the 64 counters only

    dim3 g1(8, 32);   // 8 chunks x 32 batches
    snn_spike_compact<<<g1, 256, 0, stream>>>(
        V, a, Xd, Xext, dmap_int, dmap_ext, out, cnt, list_int, list_ext);

    dim3 g2(16, 32);  // 16 col-tiles x 32 batches
    snn_current<<<g2, 64, 0, stream>>>(W_int, W_ext, V, out, cnt, list_int, list_ext);
}

// Round 3
// 145.890 us; speedup vs baseline: 1.4425x; 1.0270x over previous
//
#include <hip/hip_runtime.h>

// SNN ALIF step, B=32, N=4096, D=8, NE=2048, DE=4.
// K1: per-(chunk,batch) block: spikes + adaptation, LDS-compacted active-source
//     lists written to per-chunk segments with per-chunk counts (NO global
//     atomics, NO counter zero-init needed).
// K2: per (256-col tile, batch) block, 4 waves: prefix-merge chunk lists into
//     LDS, row-split across waves, depth-8 float4 software pipeline over W rows,
//     LDS combine, fused membrane-update epilogue.

#define B_   32
#define N_   4096
#define D_   8
#define NE_  2048
#define DE_  4
#define BN_  (B_ * N_)
#define BNE_ (B_ * NE_)
#define NCH_ 8          // chunks per batch (both int and ext)
#define CI_  512        // int neurons per chunk
#define CE_  256        // ext sources per chunk

// ---------------- K1: spike + compact ----------------
__global__ __launch_bounds__(256) void snn_spike_compact(
    const float* __restrict__ V, const float* __restrict__ a,
    const float* __restrict__ Xd, const float* __restrict__ Xext,
    const float* __restrict__ dmap_int, const float* __restrict__ dmap_ext,
    float* __restrict__ out,
    int* __restrict__ cnt_int, int* __restrict__ cnt_ext,
    unsigned short* __restrict__ list_int, unsigned short* __restrict__ list_ext)
{
#pragma clang fp contract(off)
    // exact op order for th: a 1-ulp difference can flip a spike (absmax 1.0)
    __shared__ unsigned short s_i[CI_];
    __shared__ unsigned short s_e[CE_];
    __shared__ int lc_i, lc_e;
    int tid = threadIdx.x;
    if (tid == 0) { lc_i = 0; lc_e = 0; }
    __syncthreads();

    int b = blockIdx.y;
    int c = blockIdx.x;

    #pragma unroll
    for (int r = 0; r < 2; ++r) {
        int i = c * CI_ + r * 256 + tid;
        int t = b * N_ + i;
        float av = a[t];
        float vv = V[t];
        float th = 1.0f + 1.8f * av;
        float x = (vv - th >= 0.0f) ? 1.0f : 0.0f;
        out[t] = x;                          // X
        out[2 * BN_ + t] = 0.98f * av + x;   // a_new
        int di = 0;
        #pragma unroll
        for (int d = 1; d < D_; ++d)
            if (dmap_int[d * N_ + i] != 0.0f) di = d;
        // Xd_new[0] = X, Xd_new[d>=1] = Xd[d-1]
        float xi = (di == 0) ? x : Xd[(di - 1) * BN_ + t];
        if (xi != 0.0f) {
            int p = atomicAdd(&lc_i, 1);     // LDS atomic only
            s_i[p] = (unsigned short)i;
        }
    }
    {
        int j = c * CE_ + tid;
        int u = b * NE_ + j;
        int de = 0;
        #pragma unroll
        for (int d = 1; d < DE_; ++d)
            if (dmap_ext[d * NE_ + j] != 0.0f) de = d;
        float xe = Xext[de * BNE_ + u];      // external: no shift
        if (xe != 0.0f) {
            int p = atomicAdd(&lc_e, 1);
            s_e[p] = (unsigned short)j;
        }
    }
    __syncthreads();
    // per-chunk segmented output: plain stores, deterministic, no zeroing needed
    if (tid == 0) {
        cnt_int[b * NCH_ + c] = lc_i;
        cnt_ext[b * NCH_ + c] = lc_e;
    }
    for (int k = tid; k < lc_i; k += 256) list_int[b * N_  + c * CI_ + k] = s_i[k];
    for (int k = tid; k < lc_e; k += 256) list_ext[b * NE_ + c * CE_ + k] = s_e[k];
}

// ---------------- K2: gather-accumulate W rows ----------------
__device__ __forceinline__ float4 ld4(const float* p) { return *(const float4*)p; }
__device__ __forceinline__ void add4(float4& a, const float4 w) {
    a.x += w.x; a.y += w.y; a.z += w.z; a.w += w.w;
}

// Accumulate n rows of W (row stride N_) at column j; indices in LDS (sl,
// 16B-aligned). Depth-8 software pipeline: 8-16 float4 loads in flight.
__device__ __forceinline__ void accum_rows(const float* __restrict__ W,
                                           const unsigned short* sl, int n, int j,
                                           float4& acc)
{
    if (n <= 0) return;
    int nf = n & ~7;
    if (nf >= 8) {
        uint4 g = *(const uint4*)(sl);   // 8 indices, LDS broadcast
        float4 p0 = ld4(W + (size_t)(g.x & 0xffff) * N_ + j);
        float4 p1 = ld4(W + (size_t)(g.x >> 16)    * N_ + j);
        float4 p2 = ld4(W + (size_t)(g.y & 0xffff) * N_ + j);
        float4 p3 = ld4(W + (size_t)(g.y >> 16)    * N_ + j);
        float4 p4 = ld4(W + (size_t)(g.z & 0xffff) * N_ + j);
        float4 p5 = ld4(W + (size_t)(g.z >> 16)    * N_ + j);
        float4 p6 = ld4(W + (size_t)(g.w & 0xffff) * N_ + j);
        float4 p7 = ld4(W + (size_t)(g.w >> 16)    * N_ + j);
        for (int k = 8; k < nf; k += 8) {
            uint4 g2 = *(const uint4*)(sl + k);
            float4 q0 = ld4(W + (size_t)(g2.x & 0xffff) * N_ + j);
            float4 q1 = ld4(W + (size_t)(g2.x >> 16)    * N_ + j);
            float4 q2 = ld4(W + (size_t)(g2.y & 0xffff) * N_ + j);
            float4 q3 = ld4(W + (size_t)(g2.y >> 16)    * N_ + j);
            float4 q4 = ld4(W + (size_t)(g2.z & 0xffff) * N_ + j);
            float4 q5 = ld4(W + (size_t)(g2.z >> 16)    * N_ + j);
            float4 q6 = ld4(W + (size_t)(g2.w & 0xffff) * N_ + j);
            float4 q7 = ld4(W + (size_t)(g2.w >> 16)    * N_ + j);
            add4(acc, p0); add4(acc, p1); add4(acc, p2); add4(acc, p3);
            add4(acc, p4); add4(acc, p5); add4(acc, p6); add4(acc, p7);
            p0 = q0; p1 = q1; p2 = q2; p3 = q3;
            p4 = q4; p5 = q5; p6 = q6; p7 = q7;
        }
        add4(acc, p0); add4(acc, p1); add4(acc, p2); add4(acc, p3);
        add4(acc, p4); add4(acc, p5); add4(acc, p6); add4(acc, p7);
    }
    for (int k = nf; k < n; ++k) {
        float4 w = ld4(W + (size_t)sl[k] * N_ + j);
        add4(acc, w);
    }
}

__global__ __launch_bounds__(256) void snn_current(
    const float* __restrict__ W_int, const float* __restrict__ W_ext,
    const float* __restrict__ V, float* __restrict__ out,
    const int* __restrict__ cnt_int, const int* __restrict__ cnt_ext,
    const unsigned short* __restrict__ list_int,
    const unsigned short* __restrict__ list_ext)
{
    __shared__ __align__(16) unsigned short s_int[N_];
    __shared__ __align__(16) unsigned short s_ext[NE_];
    __shared__ float4 s_part[4][64];
    int tid = threadIdx.x;
    int b = blockIdx.y;

    // merge per-chunk segments into contiguous LDS lists (prefix over 8 counts)
    int ci[NCH_], oi[NCH_], ce[NCH_], oe[NCH_];
    int ni = 0, ne = 0;
    #pragma unroll
    for (int c = 0; c < NCH_; ++c) {
        ci[c] = cnt_int[b * NCH_ + c]; oi[c] = ni; ni += ci[c];
        ce[c] = cnt_ext[b * NCH_ + c]; oe[c] = ne; ne += ce[c];
    }
    #pragma unroll
    for (int c = 0; c < NCH_; ++c) {
        for (int k = tid; k < ci[c]; k += 256) s_int[oi[c] + k] = list_int[b * N_  + c * CI_ + k];
        for (int k = tid; k < ce[c]; k += 256) s_ext[oe[c] + k] = list_ext[b * NE_ + c * CE_ + k];
    }
    __syncthreads();

    int w = tid >> 6, lane = tid & 63;
    int j = blockIdx.x * 256 + lane * 4;
    float4 acc = make_float4(0.f, 0.f, 0.f, 0.f);

    // row-split across the 4 waves; slice starts 8-aligned (16B for uint4 reads)
    int qi = ((ni + 31) >> 5) << 3;                  // ceil(ni/4) rounded up to x8
    int si = w * qi;
    accum_rows(W_int, s_int + si, min(ni, si + qi) - si, j, acc);
    int qe = ((ne + 31) >> 5) << 3;
    int se = w * qe;
    accum_rows(W_ext, s_ext + se, min(ne, se + qe) - se, j, acc);

    s_part[w][lane] = acc;
    __syncthreads();
    if (w == 0) {
        float4 a0 = s_part[0][lane], a1 = s_part[1][lane];
        float4 a2 = s_part[2][lane], a3 = s_part[3][lane];
        float4 cur;
        cur.x = (a0.x + a1.x) + (a2.x + a3.x);
        cur.y = (a0.y + a1.y) + (a2.y + a3.y);
        cur.z = (a0.z + a1.z) + (a2.z + a3.z);
        cur.w = (a0.w + a1.w) + (a2.w + a3.w);
        // fused: V_new = ALPHA*V*(1-X) + current
        int t = b * N_ + j;
        float4 v = ld4(V + t);
        float4 x = ld4(out + t);      // X written by K1
        float4 vn;
        vn.x = 0.95f * v.x * (1.0f - x.x) + cur.x;
        vn.y = 0.95f * v.y * (1.0f - x.y) + cur.y;
        vn.z = 0.95f * v.z * (1.0f - x.z) + cur.z;
        vn.w = 0.95f * v.w * (1.0f - x.w) + cur.w;
        *(float4*)(out + BN_ + t) = vn;
    }
}

extern "C" void kernel_launch(void* const* d_in, const int* in_sizes, int n_in,
                              void* d_out, int out_size, void* d_ws, size_t ws_size,
                              hipStream_t stream)
{
    const float* V        = (const float*)d_in[0];
    const float* a        = (const float*)d_in[1];
    const float* Xd       = (const float*)d_in[2];
    const float* Xext     = (const float*)d_in[3];
    const float* W_int    = (const float*)d_in[4];
    const float* W_ext    = (const float*)d_in[5];
    const float* dmap_int = (const float*)d_in[6];
    const float* dmap_ext = (const float*)d_in[7];
    float* out = (float*)d_out;

    // ws layout: cnt_int[256] | cnt_ext[256] | list_int[B*N u16] | list_ext[B*NE u16]
    int* cnt_int = (int*)d_ws;
    int* cnt_ext = (int*)((char*)d_ws + 1024);
    unsigned short* list_int = (unsigned short*)((char*)d_ws + 2048);
    unsigned short* list_ext = (unsigned short*)((char*)d_ws + 2048 + (size_t)BN_ * 2);

    dim3 g1(NCH_, B_);
    snn_spike_compact<<<g1, 256, 0, stream>>>(
        V, a, Xd, Xext, dmap_int, dmap_ext, out, cnt_int, cnt_ext, list_int, list_ext);

    dim3 g2(16, B_);   // 16 col-tiles x 32 batches, 4 waves each
    snn_current<<<g2, 256, 0, stream>>>(
        W_int, W_ext, V, out, cnt_int, cnt_ext, list_int, list_ext);
}